// Round 4
// baseline (882.507 us; speedup 1.0000x reference)
//
#include <hip/hip_runtime.h>

// GCN 2-layer + mean-pool + readout, transform-first formulation:
//   z[u]  = (norm_out[u]*x[u]) @ W1            (dense GEMM, z in bf16)
//   h1[n] = relu( norm_in[n] * Sum_{e:dst=n} z[src_e] + b1 )   (unweighted gather!)
//   out   = ((1/N) Sum_n cw[n]*h1[n]) @ W2 + b2 @ Wr^T + br
//   cw[n] = norm_out[n] * c_raw[n],  c_raw[u] = Sum_{e:src=u} norm_in[dst_e]
// CSR by dst with per-node slot counts padded to x8; pad slots -> zero row ZROW.

constexpr int NN = 50000;
constexpr int NE = 800000;
constexpr int ZROW = NN;            // appended zero feature row
constexpr int NW = 48;              // 96 bf16 = 48 u32 words per z row

// ws dword offsets
constexpr int OFF_DEG_OUT = 0;        // int[50000]  zeroed
constexpr int OFF_DEG_IN  = 50000;    // int[50000]  zeroed
constexpr int OFF_CRAW    = 100000;   // f32[50000]  zeroed
constexpr int OFF_SVEC    = 150000;   // f32[96]     zeroed
constexpr int OFF_TICKET  = 150096;   // int         zeroed
constexpr int OFF_TILECTR = 150097;   // int         zeroed
constexpr size_t ZERO_DW  = 150112;
constexpr int OFF_ROW_PTR = 150112;   // int[50001] (padded offsets)
constexpr int OFF_CURSOR  = 200160;   // int[50000]
constexpr int OFF_SLOTS   = 250160;   // int[1.2M]
constexpr int SLOTS_CAP   = 1200000;
constexpr int OFF_Z       = 1450160;  // u32[50001*48]

__device__ __forceinline__ unsigned cvbf(float x) {
  unsigned u = __float_as_uint(x);
  return (u + 0x7FFFu + ((u >> 16) & 1u)) >> 16;
}
__device__ __forceinline__ float bflo(unsigned u) { return __uint_as_float(u << 16); }
__device__ __forceinline__ float bfhi(unsigned u) { return __uint_as_float(u & 0xFFFF0000u); }

__global__ void k_deg(const int4* __restrict__ src4, const int4* __restrict__ dst4,
                      int* __restrict__ deg_out, int* __restrict__ deg_in) {
  int i = blockIdx.x * blockDim.x + threadIdx.x;
  if (i < NE / 4) {
    int4 s = src4[i], d = dst4[i];
    atomicAdd(&deg_out[s.x], 1); atomicAdd(&deg_out[s.y], 1);
    atomicAdd(&deg_out[s.z], 1); atomicAdd(&deg_out[s.w], 1);
    atomicAdd(&deg_in[d.x], 1);  atomicAdd(&deg_in[d.y], 1);
    atomicAdd(&deg_in[d.z], 1);  atomicAdd(&deg_in[d.w], 1);
  }
}

// blocks [0,1024): z = (norm_out*x)@W1 -> bf16 words. blocks [1024,1320): fill
// slots with ZROW. block 1320: zero z's ZROW row.
__global__ __launch_bounds__(256)
void k_gemm(const float* __restrict__ x, const int* __restrict__ deg_out,
            const float* __restrict__ W1, unsigned* __restrict__ zw,
            int* __restrict__ slots) {
  int tid = threadIdx.x;
  if (blockIdx.x >= 1024) {
    int fb = blockIdx.x - 1024;
    if (fb < 296) {
      for (int i = fb * 256 + tid; i < SLOTS_CAP; i += 296 * 256) slots[i] = ZROW;
    } else {
      if (tid < NW) zw[(size_t)ZROW * NW + tid] = 0u;
    }
    return;
  }
  __shared__ float W1s[96 * 96];
  for (int i = tid; i < 96 * 96 / 4; i += 256)
    ((float4*)W1s)[i] = ((const float4*)W1)[i];
  __syncthreads();

  int wave = tid >> 6, ll = tid & 31, hl = (tid >> 5) & 1;
  for (int task = blockIdx.x * 4 + wave; task < NN / 2; task += 1024 * 4) {
    int n = task * 2 + hl;
    float no = rsqrtf((float)max(deg_out[n], 1));
    const float* xr = x + (size_t)n * 96;
    float v0 = xr[ll] * no, v1 = xr[ll + 32] * no, v2 = xr[ll + 64] * no;
    float h0 = 0.f, h1 = 0.f, h2 = 0.f;
#pragma unroll
    for (int kb = 0; kb < 3; ++kb) {
      float vsrc = kb == 0 ? v0 : (kb == 1 ? v1 : v2);
#pragma unroll
      for (int kk = 0; kk < 32; ++kk) {
        int k = kb * 32 + kk;
        float vk = __shfl(vsrc, kk, 32);
        h0 = fmaf(vk, W1s[k * 96 + ll], h0);
        h1 = fmaf(vk, W1s[k * 96 + ll + 32], h1);
        h2 = fmaf(vk, W1s[k * 96 + ll + 64], h2);
      }
    }
    float p0 = __shfl_xor(h0, 1), p1 = __shfl_xor(h1, 1), p2 = __shfl_xor(h2, 1);
    if (!(ll & 1)) {                       // even lane packs (self=low, partner=high)
      unsigned* zr = zw + (size_t)n * NW + (ll >> 1);
      zr[0]  = cvbf(h0) | (cvbf(p0) << 16);
      zr[16] = cvbf(h1) | (cvbf(p1) << 16);
      zr[32] = cvbf(h2) | (cvbf(p2) << 16);
    }
  }
}

// Exclusive scan of padded degree (ceil(deg/8)*8) -> row_ptr, cursor. 1 block.
__global__ void k_scan(const int* __restrict__ deg_in,
                       int* __restrict__ row_ptr, int* __restrict__ cursor) {
  __shared__ int part[1024];
  const int CH = 49;                 // 1024*49 = 50176 >= NN
  int t = threadIdx.x;
  int base = t * CH, s = 0;
  for (int i = 0; i < CH; ++i) {
    int idx = base + i;
    if (idx < NN) s += ((deg_in[idx] + 7) & ~7);
  }
  part[t] = s;
  __syncthreads();
  for (int off = 1; off < 1024; off <<= 1) {
    int v = (t >= off) ? part[t - off] : 0;
    __syncthreads();
    part[t] += v;
    __syncthreads();
  }
  int run = part[t] - s;
  for (int i = 0; i < CH; ++i) {
    int idx = base + i;
    if (idx < NN) {
      row_ptr[idx] = run; cursor[idx] = run;
      run += ((deg_in[idx] + 7) & ~7);
    }
  }
  if (t == 1023) row_ptr[NN] = part[1023];
}

// Counting sort by dst (2 edges/thread) + c_raw scatter.
__global__ void k_scatter(const int2* __restrict__ src2, const int2* __restrict__ dst2,
                          const int* __restrict__ deg_in, int* __restrict__ cursor,
                          int* __restrict__ slots, float* __restrict__ c_raw) {
  int i = blockIdx.x * blockDim.x + threadIdx.x;
  if (i < NE / 2) {
    int2 s = src2[i], d = dst2[i];
    int p0 = atomicAdd(&cursor[d.x], 1);
    int p1 = atomicAdd(&cursor[d.y], 1);
    slots[p0] = s.x;
    slots[p1] = s.y;
    atomicAdd(&c_raw[s.x], rsqrtf((float)max(deg_in[d.x], 1)));
    atomicAdd(&c_raw[s.y], rsqrtf((float)max(deg_in[d.y], 1)));
  }
}

// Gather z rows (unweighted, 8-deep pipelined), relu epilogue, global weighted
// sum; last block computes the final two matvecs.
__global__ __launch_bounds__(256)
void k_gather(const unsigned* __restrict__ zw,
              const int* __restrict__ deg_in, const int* __restrict__ deg_out,
              const float* __restrict__ c_raw,
              const int* __restrict__ row_ptr, const int* __restrict__ slots,
              const float* __restrict__ b1,
              const float* __restrict__ W2, const float* __restrict__ b2,
              const float* __restrict__ Wr, const float* __restrict__ br,
              int* __restrict__ tilectr, int* __restrict__ ticket,
              float* __restrict__ svec, float* __restrict__ out) {
  __shared__ float red[96];
  __shared__ float sg[96], hg[96];
  __shared__ int lastflag;
  int tid = threadIdx.x, l = tid & 63;
  if (tid < 96) red[tid] = 0.f;
  __syncthreads();

  float bb0 = 0.f, bb1 = 0.f;
  if (l < 48) { bb0 = b1[2 * l]; bb1 = b1[2 * l + 1]; }
  float a0 = 0.f, a1 = 0.f;

  const int NTILES = NN / 4;        // 12500
  int tile = 0;
  if (l == 0) tile = atomicAdd(tilectr, 1);
  tile = __shfl(tile, 0, 64);

  while (tile < NTILES) {
    int nxt = 0;
    if (l == 0) nxt = atomicAdd(tilectr, 1);   // claim-ahead hides latency
    nxt = __shfl(nxt, 0, 64);

    int n0 = tile * 4;
    // per-tile metadata via lanes
    int rp = 0, di = 0, dg = 0; float cr = 0.f;
    if (l < 5)              rp = row_ptr[n0 + l];
    if (l >= 8  && l < 12)  di = deg_in[n0 + (l - 8)];
    if (l >= 12 && l < 16)  dg = deg_out[n0 + (l - 12)];
    if (l >= 16 && l < 20)  cr = c_raw[n0 + (l - 16)];
    int E0 = __shfl(rp, 0, 64);
    // tile's slot list (up to 192 slots; Poisson(64)+pad -> overflow ~never)
    int sA = slots[min(E0 + l,       SLOTS_CAP - 1)];
    int sB = slots[min(E0 + 64 + l,  SLOTS_CAP - 1)];
    int sC = slots[min(E0 + 128 + l, SLOTS_CAP - 1)];

#pragma unroll 1
    for (int j = 0; j < 4; ++j) {
      int e0 = __shfl(rp, j, 64) - E0;
      int e1 = __shfl(rp, j + 1, 64) - E0;   // j==3 uses lane 4 = row_ptr[n0+4]
      float v0 = 0.f, v1 = 0.f;

      auto ldrow = [&](int t) -> unsigned {
        int sv = (t < 64) ? sA : ((t < 128) ? sB : sC);
        int s = __shfl(sv, t, 64);           // &63 wrap lands on the right lane
        if (t >= 192) s = slots[E0 + t];     // near-impossible fallback
        unsigned u = 0u;
        if (l < 48) u = zw[(size_t)s * NW + l];
        return u;
      };

      int t = e0;
      unsigned r0, r1, r2, r3, r4, r5, r6, r7;
      if (t < e1) {
        r0 = ldrow(t);     r1 = ldrow(t + 1); r2 = ldrow(t + 2); r3 = ldrow(t + 3);
        r4 = ldrow(t + 4); r5 = ldrow(t + 5); r6 = ldrow(t + 6); r7 = ldrow(t + 7);
      }
      while (t < e1) {
        unsigned c0 = r0, c1 = r1, c2 = r2, c3 = r3,
                 c4 = r4, c5 = r5, c6 = r6, c7 = r7;
        t += 8;
        if (t < e1) {                         // prefetch next block of 8 rows
          r0 = ldrow(t);     r1 = ldrow(t + 1); r2 = ldrow(t + 2); r3 = ldrow(t + 3);
          r4 = ldrow(t + 4); r5 = ldrow(t + 5); r6 = ldrow(t + 6); r7 = ldrow(t + 7);
        }
        float slo = ((bflo(c0) + bflo(c1)) + (bflo(c2) + bflo(c3))) +
                    ((bflo(c4) + bflo(c5)) + (bflo(c6) + bflo(c7)));
        float shi = ((bfhi(c0) + bfhi(c1)) + (bfhi(c2) + bfhi(c3))) +
                    ((bfhi(c4) + bfhi(c5)) + (bfhi(c6) + bfhi(c7)));
        v0 += slo; v1 += shi;
      }

      float ni = rsqrtf((float)max(__shfl(di, 8 + j, 64), 1));
      float cw = rsqrtf((float)max(__shfl(dg, 12 + j, 64), 1)) * __shfl(cr, 16 + j, 64);
      if (l < 48) {
        float h0 = fmaxf(fmaf(ni, v0, bb0), 0.f);
        float h1 = fmaxf(fmaf(ni, v1, bb1), 0.f);
        a0 = fmaf(cw, h0, a0);
        a1 = fmaf(cw, h1, a1);
      }
    }
    tile = nxt;
  }

  if (l < 48) { atomicAdd(&red[2 * l], a0); atomicAdd(&red[2 * l + 1], a1); }
  __syncthreads();
  if (tid < 96) atomicAdd(&svec[tid], red[tid]);
  __threadfence();
  __syncthreads();
  if (tid == 0) {
    int tk = atomicAdd(ticket, 1);
    lastflag = (tk == (int)gridDim.x - 1);
  }
  __syncthreads();
  if (lastflag) {
    if (tid < 96) sg[tid] = atomicAdd(&svec[tid], 0.0f);  // coherent read
    __syncthreads();
    if (tid < 96) {
      float acc = b2[tid];
      const float invN = 1.0f / (float)NN;
      for (int k = 0; k < 96; ++k)
        acc = fmaf(sg[k] * invN, W2[k * 96 + tid], acc);
      hg[tid] = acc;
    }
    __syncthreads();
    if (tid < 8) {
      float acc = br[tid];
      for (int k = 0; k < 96; ++k)
        acc = fmaf(hg[k], Wr[tid * 96 + k], acc);
      out[tid] = acc;
    }
  }
}

extern "C" void kernel_launch(void* const* d_in, const int* in_sizes, int n_in,
                              void* d_out, int out_size, void* d_ws, size_t ws_size,
                              hipStream_t stream) {
  const float* feats = (const float*)d_in[0];
  const int*   src   = (const int*)d_in[1];
  const int*   dst   = (const int*)d_in[2];
  const float* W1    = (const float*)d_in[3];
  const float* b1    = (const float*)d_in[4];
  const float* W2    = (const float*)d_in[5];
  const float* b2    = (const float*)d_in[6];
  const float* Wr    = (const float*)d_in[7];
  const float* br    = (const float*)d_in[8];
  float* out = (float*)d_out;

  int*   wsi = (int*)d_ws;
  float* wsf = (float*)d_ws;
  int*   deg_out = wsi + OFF_DEG_OUT;
  int*   deg_in  = wsi + OFF_DEG_IN;
  float* c_raw   = wsf + OFF_CRAW;
  float* svec    = wsf + OFF_SVEC;
  int*   ticket  = wsi + OFF_TICKET;
  int*   tilectr = wsi + OFF_TILECTR;
  int*   row_ptr = wsi + OFF_ROW_PTR;
  int*   cursor  = wsi + OFF_CURSOR;
  int*   slots   = wsi + OFF_SLOTS;
  unsigned* zw   = (unsigned*)(wsi + OFF_Z);

  hipMemsetAsync(d_ws, 0, ZERO_DW * 4, stream);

  k_deg<<<(NE / 4 + 255) / 256, 256, 0, stream>>>((const int4*)src, (const int4*)dst,
                                                  deg_out, deg_in);
  k_gemm<<<1321, 256, 0, stream>>>(feats, deg_out, W1, zw, slots);
  k_scan<<<1, 1024, 0, stream>>>(deg_in, row_ptr, cursor);
  k_scatter<<<(NE / 2 + 255) / 256, 256, 0, stream>>>((const int2*)src, (const int2*)dst,
                                                      deg_in, cursor, slots, c_raw);
  k_gather<<<2048, 256, 0, stream>>>(zw, deg_in, deg_out, c_raw, row_ptr, slots,
                                     b1, W2, b2, Wr, br, tilectr, ticket, svec, out);
}

// Round 5
// 698.713 us; speedup vs baseline: 1.2630x; 1.2630x over previous
//
#include <hip/hip_runtime.h>

// GCN 2-layer + mean-pool + readout, transform-first:
//   z[u]  = (norm_out[u]*x[u]) @ W1                     (f32, dense)
//   h1[n] = relu( norm_in[n] * Sum_{e:dst=n} z[src_e] + b1 )
//   out   = ((1/N) Sum_n cw[n]*h1[n]) @ W2 + b2 @ Wr^T + br
//   cw[n] = norm_out[n]*c_raw[n],  c_raw[u] = Sum_{e:src=u} norm_in[dst_e]
// Per-node in-edge segments allocated by wave-level atomic alloc (order
// scrambled, irrelevant); per-node slot count padded to EVEN, pads -> ZROW
// (zero z row). Gather: one full wave per 4-node tile, 2 edges/node/round.

constexpr int NN = 50000;
constexpr int NE = 800000;
constexpr int ZROW = NN;

// ws dword offsets
constexpr int OFF_DEG_OUT = 0;        // int[50000]  zeroed
constexpr int OFF_DEG_IN  = 50000;    // int[50000]  zeroed
constexpr int OFF_CRAW    = 100000;   // f32[50000]  zeroed
constexpr int OFF_SVEC    = 150000;   // f32[96]     zeroed
constexpr int OFF_TICKET  = 150096;   // int zeroed
constexpr int OFF_TILECTR = 150097;   // int zeroed
constexpr int OFF_ALLOC   = 150098;   // int zeroed
constexpr size_t ZERO_DW  = 150112;
constexpr int OFF_ROW_PTR = 150112;   // int[50000]
constexpr int OFF_CURSOR  = 200112;   // int[50000]
constexpr int OFF_SLOTS   = 250112;   // int[1000000] (prefilled ZROW)
constexpr int SLOTS_CAP   = 1000000;
constexpr int OFF_Z       = 1250112;  // f32[(50001)*96]

__global__ void k_deg(const int4* __restrict__ src4, const int4* __restrict__ dst4,
                      int* __restrict__ deg_out, int* __restrict__ deg_in) {
  int i = blockIdx.x * blockDim.x + threadIdx.x;
  if (i < NE / 4) {
    int4 s = src4[i], d = dst4[i];
    atomicAdd(&deg_out[s.x], 1); atomicAdd(&deg_out[s.y], 1);
    atomicAdd(&deg_out[s.z], 1); atomicAdd(&deg_out[s.w], 1);
    atomicAdd(&deg_in[d.x], 1);  atomicAdd(&deg_in[d.y], 1);
    atomicAdd(&deg_in[d.z], 1);  atomicAdd(&deg_in[d.w], 1);
  }
}

// blocks [0,1024): z = (norm_out*x)@W1 (f32 out). blocks [1024,1088): fill
// slots[] with ZROW. block 1088: zero z's ZROW row.
__global__ __launch_bounds__(256)
void k_gemm(const float* __restrict__ x, const int* __restrict__ deg_out,
            const float* __restrict__ W1, float* __restrict__ z,
            int* __restrict__ slots) {
  int tid = threadIdx.x;
  if (blockIdx.x >= 1024) {
    int fb = blockIdx.x - 1024;
    if (fb < 64) {
      int4 zr4 = make_int4(ZROW, ZROW, ZROW, ZROW);
      for (int i = fb * 256 + tid; i < SLOTS_CAP / 4; i += 64 * 256)
        ((int4*)slots)[i] = zr4;
    } else {
      if (tid < 96) z[(size_t)ZROW * 96 + tid] = 0.f;
    }
    return;
  }
  __shared__ float W1s[96 * 96];
  for (int i = tid; i < 96 * 96 / 4; i += 256)
    ((float4*)W1s)[i] = ((const float4*)W1)[i];
  __syncthreads();

  int wave = tid >> 6, ll = tid & 31, hl = (tid >> 5) & 1;
  for (int task = blockIdx.x * 4 + wave; task < NN / 2; task += 1024 * 4) {
    int n = task * 2 + hl;
    float no = rsqrtf((float)max(deg_out[n], 1));
    const float* xr = x + (size_t)n * 96;
    float v0 = xr[ll] * no, v1 = xr[ll + 32] * no, v2 = xr[ll + 64] * no;
    float h0 = 0.f, h1 = 0.f, h2 = 0.f;
#pragma unroll
    for (int kb = 0; kb < 3; ++kb) {
      float vsrc = kb == 0 ? v0 : (kb == 1 ? v1 : v2);
#pragma unroll
      for (int kk = 0; kk < 32; ++kk) {
        int k = kb * 32 + kk;
        float vk = __shfl(vsrc, kk, 32);
        h0 = fmaf(vk, W1s[k * 96 + ll], h0);
        h1 = fmaf(vk, W1s[k * 96 + ll + 32], h1);
        h2 = fmaf(vk, W1s[k * 96 + ll + 64], h2);
      }
    }
    float* zr = z + (size_t)n * 96;
    zr[ll] = h0; zr[ll + 32] = h1; zr[ll + 64] = h2;
  }
}

// Wave-level segment allocation: pd = deg_in padded to even; wave prefix-scan,
// one atomicAdd(alloc) per wave. Writes row_ptr and cursor.
__global__ void k_alloc(const int* __restrict__ deg_in, int* __restrict__ alloc,
                        int* __restrict__ row_ptr, int* __restrict__ cursor) {
  int n = blockIdx.x * blockDim.x + threadIdx.x;
  int l = threadIdx.x & 63;
  int pd = 0;
  if (n < NN) pd = (deg_in[n] + 1) & ~1;
  int incl = pd;
#pragma unroll
  for (int o = 1; o < 64; o <<= 1) {
    int u = __shfl_up(incl, o, 64);
    if (l >= o) incl += u;
  }
  int base = 0;
  if (l == 63) base = atomicAdd(alloc, incl);   // lane 63 holds wave total
  base = __shfl(base, 63, 64);
  if (n < NN) { int p = base + incl - pd; row_ptr[n] = p; cursor[n] = p; }
}

// Counting scatter by dst (unsorted segments) + c_raw accumulation.
__global__ void k_scatter(const int2* __restrict__ src2, const int2* __restrict__ dst2,
                          const int* __restrict__ deg_in, int* __restrict__ cursor,
                          int* __restrict__ slots, float* __restrict__ c_raw) {
  int i = blockIdx.x * blockDim.x + threadIdx.x;
  if (i < NE / 2) {
    int2 s = src2[i], d = dst2[i];
    int p0 = atomicAdd(&cursor[d.x], 1);
    int p1 = atomicAdd(&cursor[d.y], 1);
    slots[p0] = s.x;
    slots[p1] = s.y;
    atomicAdd(&c_raw[s.x], rsqrtf((float)max(deg_in[d.x], 1)));
    atomicAdd(&c_raw[s.y], rsqrtf((float)max(deg_in[d.y], 1)));
  }
}

// One full wave per 4-node tile; per round each node consumes 2 edges
// (half-wave A loads row s0, half-wave B row s1) -> 12 loads in flight/lane.
__global__ __launch_bounds__(256, 8)
void k_gather(const float* __restrict__ z,
              const int* __restrict__ deg_in, const int* __restrict__ deg_out,
              const float* __restrict__ c_raw,
              const int* __restrict__ row_ptr, const int* __restrict__ slots,
              const float* __restrict__ b1,
              const float* __restrict__ W2, const float* __restrict__ b2,
              const float* __restrict__ Wr, const float* __restrict__ br,
              int* __restrict__ tilectr, int* __restrict__ ticket,
              float* __restrict__ svec, float* __restrict__ out) {
  __shared__ float red[96];
  __shared__ float sg[96], hg[96];
  __shared__ int lastflag;
  const int tid = threadIdx.x, l = tid & 63;
  const int ll = l & 31, half = l >> 5;
  if (tid < 96) red[tid] = 0.f;
  __syncthreads();

  float bb0 = b1[ll], bb1 = b1[ll + 32], bb2 = b1[ll + 64];
  float as0 = 0.f, as1 = 0.f, as2 = 0.f;

  const int NTILES = NN / 4;
  for (;;) {
    int tile = 0;
    if (l == 0) tile = atomicAdd(tilectr, 1);
    tile = __shfl(tile, 0, 64);
    if (tile >= NTILES) break;
    int n0 = tile * 4;

    // metadata via lanes 0..15
    int mrp = 0, mdi = 0, mdg = 0; float mcr = 0.f;
    if (l < 4)              mrp = row_ptr[n0 + l];
    else if (l < 8)         mdi = deg_in[n0 + (l - 4)];
    else if (l < 12)        mdg = deg_out[n0 + (l - 8)];
    else if (l < 16)        mcr = c_raw[n0 + (l - 12)];
    int rp0 = __shfl(mrp, 0, 64), rp1 = __shfl(mrp, 1, 64),
        rp2 = __shfl(mrp, 2, 64), rp3 = __shfl(mrp, 3, 64);
    int di0 = __shfl(mdi, 4, 64), di1 = __shfl(mdi, 5, 64),
        di2 = __shfl(mdi, 6, 64), di3 = __shfl(mdi, 7, 64);
    int pd0 = (di0 + 1) & ~1, pd1 = (di1 + 1) & ~1,
        pd2 = (di2 + 1) & ~1, pd3 = (di3 + 1) & ~1;
    // slot banks: 64 slots per node in registers
    int bk0 = slots[rp0 + l], bk1 = slots[rp1 + l],
        bk2 = slots[rp2 + l], bk3 = slots[rp3 + l];

    float v00 = 0.f, v01 = 0.f, v02 = 0.f;
    float v10 = 0.f, v11 = 0.f, v12 = 0.f;
    float v20 = 0.f, v21 = 0.f, v22 = 0.f;
    float v30 = 0.f, v31 = 0.f, v32 = 0.f;

    int maxpd = max(max(pd0, pd1), max(pd2, pd3));
#pragma unroll 1
    for (int t = 0; t < maxpd; t += 2) {
      int s0, s1, s2, s3;
      if (t < 64) {
        int idx = t + half;
        s0 = __shfl(bk0, idx, 64); s1 = __shfl(bk1, idx, 64);
        s2 = __shfl(bk2, idx, 64); s3 = __shfl(bk3, idx, 64);
      } else {            // deg > 64: rare fallback, uniform-ish loads
        s0 = slots[rp0 + t + half]; s1 = slots[rp1 + t + half];
        s2 = slots[rp2 + t + half]; s3 = slots[rp3 + t + half];
      }
      s0 = (t < pd0) ? s0 : ZROW;
      s1 = (t < pd1) ? s1 : ZROW;
      s2 = (t < pd2) ? s2 : ZROW;
      s3 = (t < pd3) ? s3 : ZROW;
      const float* r0 = z + (size_t)s0 * 96 + ll;
      const float* r1 = z + (size_t)s1 * 96 + ll;
      const float* r2 = z + (size_t)s2 * 96 + ll;
      const float* r3 = z + (size_t)s3 * 96 + ll;
      float a00 = r0[0], a01 = r0[32], a02 = r0[64];
      float a10 = r1[0], a11 = r1[32], a12 = r1[64];
      float a20 = r2[0], a21 = r2[32], a22 = r2[64];
      float a30 = r3[0], a31 = r3[32], a32 = r3[64];
      v00 += a00; v01 += a01; v02 += a02;
      v10 += a10; v11 += a11; v12 += a12;
      v20 += a20; v21 += a21; v22 += a22;
      v30 += a30; v31 += a31; v32 += a32;
    }
    // fold the two halves (half A holds even-edge sums, B odd-edge sums)
    v00 += __shfl_xor(v00, 32, 64); v01 += __shfl_xor(v01, 32, 64); v02 += __shfl_xor(v02, 32, 64);
    v10 += __shfl_xor(v10, 32, 64); v11 += __shfl_xor(v11, 32, 64); v12 += __shfl_xor(v12, 32, 64);
    v20 += __shfl_xor(v20, 32, 64); v21 += __shfl_xor(v21, 32, 64); v22 += __shfl_xor(v22, 32, 64);
    v30 += __shfl_xor(v30, 32, 64); v31 += __shfl_xor(v31, 32, 64); v32 += __shfl_xor(v32, 32, 64);

    int dg0 = __shfl(mdg, 8, 64),  dg1 = __shfl(mdg, 9, 64),
        dg2 = __shfl(mdg, 10, 64), dg3 = __shfl(mdg, 11, 64);
    float cr0 = __shfl(mcr, 12, 64), cr1 = __shfl(mcr, 13, 64),
          cr2 = __shfl(mcr, 14, 64), cr3 = __shfl(mcr, 15, 64);

    float ni, cw;
    ni = rsqrtf((float)max(di0, 1)); cw = rsqrtf((float)max(dg0, 1)) * cr0;
    as0 = fmaf(cw, fmaxf(fmaf(ni, v00, bb0), 0.f), as0);
    as1 = fmaf(cw, fmaxf(fmaf(ni, v01, bb1), 0.f), as1);
    as2 = fmaf(cw, fmaxf(fmaf(ni, v02, bb2), 0.f), as2);
    ni = rsqrtf((float)max(di1, 1)); cw = rsqrtf((float)max(dg1, 1)) * cr1;
    as0 = fmaf(cw, fmaxf(fmaf(ni, v10, bb0), 0.f), as0);
    as1 = fmaf(cw, fmaxf(fmaf(ni, v11, bb1), 0.f), as1);
    as2 = fmaf(cw, fmaxf(fmaf(ni, v12, bb2), 0.f), as2);
    ni = rsqrtf((float)max(di2, 1)); cw = rsqrtf((float)max(dg2, 1)) * cr2;
    as0 = fmaf(cw, fmaxf(fmaf(ni, v20, bb0), 0.f), as0);
    as1 = fmaf(cw, fmaxf(fmaf(ni, v21, bb1), 0.f), as1);
    as2 = fmaf(cw, fmaxf(fmaf(ni, v22, bb2), 0.f), as2);
    ni = rsqrtf((float)max(di3, 1)); cw = rsqrtf((float)max(dg3, 1)) * cr3;
    as0 = fmaf(cw, fmaxf(fmaf(ni, v30, bb0), 0.f), as0);
    as1 = fmaf(cw, fmaxf(fmaf(ni, v31, bb1), 0.f), as1);
    as2 = fmaf(cw, fmaxf(fmaf(ni, v32, bb2), 0.f), as2);
  }

  if (half == 0) {        // both halves hold identical sums; one writes
    atomicAdd(&red[ll], as0);
    atomicAdd(&red[ll + 32], as1);
    atomicAdd(&red[ll + 64], as2);
  }
  __syncthreads();
  if (tid < 96) atomicAdd(&svec[tid], red[tid]);
  __threadfence();
  __syncthreads();
  if (tid == 0) {
    int tk = atomicAdd(ticket, 1);
    lastflag = (tk == (int)gridDim.x - 1);
  }
  __syncthreads();
  if (lastflag) {
    if (tid < 96) sg[tid] = atomicAdd(&svec[tid], 0.0f);  // device-coherent read
    __syncthreads();
    if (tid < 96) {
      float acc = b2[tid];
      const float invN = 1.0f / (float)NN;
      for (int k = 0; k < 96; ++k)
        acc = fmaf(sg[k] * invN, W2[k * 96 + tid], acc);
      hg[tid] = acc;
    }
    __syncthreads();
    if (tid < 8) {
      float acc = br[tid];
      for (int k = 0; k < 96; ++k)
        acc = fmaf(hg[k], Wr[tid * 96 + k], acc);
      out[tid] = acc;
    }
  }
}

extern "C" void kernel_launch(void* const* d_in, const int* in_sizes, int n_in,
                              void* d_out, int out_size, void* d_ws, size_t ws_size,
                              hipStream_t stream) {
  const float* feats = (const float*)d_in[0];
  const int*   src   = (const int*)d_in[1];
  const int*   dst   = (const int*)d_in[2];
  const float* W1    = (const float*)d_in[3];
  const float* b1    = (const float*)d_in[4];
  const float* W2    = (const float*)d_in[5];
  const float* b2    = (const float*)d_in[6];
  const float* Wr    = (const float*)d_in[7];
  const float* br    = (const float*)d_in[8];
  float* out = (float*)d_out;

  int*   wsi = (int*)d_ws;
  float* wsf = (float*)d_ws;
  int*   deg_out = wsi + OFF_DEG_OUT;
  int*   deg_in  = wsi + OFF_DEG_IN;
  float* c_raw   = wsf + OFF_CRAW;
  float* svec    = wsf + OFF_SVEC;
  int*   ticket  = wsi + OFF_TICKET;
  int*   tilectr = wsi + OFF_TILECTR;
  int*   alloc   = wsi + OFF_ALLOC;
  int*   row_ptr = wsi + OFF_ROW_PTR;
  int*   cursor  = wsi + OFF_CURSOR;
  int*   slots   = wsi + OFF_SLOTS;
  float* z       = wsf + OFF_Z;

  hipMemsetAsync(d_ws, 0, ZERO_DW * 4, stream);

  k_deg<<<(NE / 4 + 255) / 256, 256, 0, stream>>>((const int4*)src, (const int4*)dst,
                                                  deg_out, deg_in);
  k_gemm<<<1089, 256, 0, stream>>>(feats, deg_out, W1, z, slots);
  k_alloc<<<(NN + 255) / 256, 256, 0, stream>>>(deg_in, alloc, row_ptr, cursor);
  k_scatter<<<(NE / 2 + 255) / 256, 256, 0, stream>>>((const int2*)src, (const int2*)dst,
                                                      deg_in, cursor, slots, c_raw);
  k_gather<<<2048, 256, 0, stream>>>(z, deg_in, deg_out, c_raw, row_ptr, slots,
                                     b1, W2, b2, Wr, br, tilectr, ticket, svec, out);
}

// Round 6
// 616.522 us; speedup vs baseline: 1.4314x; 1.1333x over previous
//
#include <hip/hip_runtime.h>

// GCN 2-layer + mean-pool + readout, transform-first:
//   z[u]  = (norm_out[u]*x[u]) @ W1                     (f32, dense)
//   h1[n] = relu( norm_in[n] * Sum_{e:dst=n} z[src_e] + b1 )
//   out   = ((1/N) Sum_n cw[n]*h1[n]) @ W2 + b2 @ Wr^T + br
//   cw[n] = norm_out[n]*c_raw[n],  c_raw[u] = Sum_{e:src=u} norm_in[dst_e]
// CSR-by-dst segments via wave-level atomic alloc (order scrambled, fine).
// Gather: one wave per 4-node tile, STATIC tile assignment (R5's single-
// address tile-counter atomic serialized the whole kernel: ~20K same-address
// RMWs x ~45cyc = 870K cyc = the entire 362us). 2-deep ping-pong prefetch.

constexpr int NN = 50000;
constexpr int NE = 800000;
constexpr int ZROW = NN;

// ws dword offsets
constexpr int OFF_DEG_OUT = 0;        // int[50000]  zeroed
constexpr int OFF_DEG_IN  = 50000;    // int[50000]  zeroed
constexpr int OFF_CRAW    = 100000;   // f32[50000]  zeroed
constexpr int OFF_SVEC    = 150000;   // f32[96]     zeroed
constexpr int OFF_TICKET  = 150096;   // int zeroed
constexpr int OFF_ALLOC   = 150097;   // int zeroed
constexpr size_t ZERO_DW  = 150112;
constexpr int OFF_ROW_PTR = 150112;   // int[50000]
constexpr int OFF_CURSOR  = 200112;   // int[50000]
constexpr int OFF_SLOTS   = 250112;   // int[1000000] (pads never read)
constexpr int SLOTS_CAP   = 1000000;
constexpr int OFF_Z       = 1250112;  // f32[(50001)*96]

__global__ void k_deg(const int4* __restrict__ src4, const int4* __restrict__ dst4,
                      int* __restrict__ deg_out, int* __restrict__ deg_in) {
  int i = blockIdx.x * blockDim.x + threadIdx.x;
  if (i < NE / 4) {
    int4 s = src4[i], d = dst4[i];
    atomicAdd(&deg_out[s.x], 1); atomicAdd(&deg_out[s.y], 1);
    atomicAdd(&deg_out[s.z], 1); atomicAdd(&deg_out[s.w], 1);
    atomicAdd(&deg_in[d.x], 1);  atomicAdd(&deg_in[d.y], 1);
    atomicAdd(&deg_in[d.z], 1);  atomicAdd(&deg_in[d.w], 1);
  }
}

// z = (norm_out*x)@W1, f32 out. 1024 blocks.
__global__ __launch_bounds__(256)
void k_gemm(const float* __restrict__ x, const int* __restrict__ deg_out,
            const float* __restrict__ W1, float* __restrict__ z) {
  int tid = threadIdx.x;
  __shared__ float W1s[96 * 96];
  for (int i = tid; i < 96 * 96 / 4; i += 256)
    ((float4*)W1s)[i] = ((const float4*)W1)[i];
  __syncthreads();

  int wave = tid >> 6, ll = tid & 31, hl = (tid >> 5) & 1;
  for (int task = blockIdx.x * 4 + wave; task < NN / 2; task += 1024 * 4) {
    int n = task * 2 + hl;
    float no = rsqrtf((float)max(deg_out[n], 1));
    const float* xr = x + (size_t)n * 96;
    float v0 = xr[ll] * no, v1 = xr[ll + 32] * no, v2 = xr[ll + 64] * no;
    float h0 = 0.f, h1 = 0.f, h2 = 0.f;
#pragma unroll
    for (int kb = 0; kb < 3; ++kb) {
      float vsrc = kb == 0 ? v0 : (kb == 1 ? v1 : v2);
#pragma unroll
      for (int kk = 0; kk < 32; ++kk) {
        int k = kb * 32 + kk;
        float vk = __shfl(vsrc, kk, 32);
        h0 = fmaf(vk, W1s[k * 96 + ll], h0);
        h1 = fmaf(vk, W1s[k * 96 + ll + 32], h1);
        h2 = fmaf(vk, W1s[k * 96 + ll + 64], h2);
      }
    }
    float* zr = z + (size_t)n * 96;
    zr[ll] = h0; zr[ll + 32] = h1; zr[ll + 64] = h2;
  }
}

// Wave-level segment alloc (pad to even); also zeroes z's ZROW row.
__global__ void k_alloc(const int* __restrict__ deg_in, int* __restrict__ alloc,
                        int* __restrict__ row_ptr, int* __restrict__ cursor,
                        float* __restrict__ z) {
  int n = blockIdx.x * blockDim.x + threadIdx.x;
  if (blockIdx.x == 0 && threadIdx.x < 96) z[(size_t)ZROW * 96 + threadIdx.x] = 0.f;
  int l = threadIdx.x & 63;
  int pd = 0;
  if (n < NN) pd = (deg_in[n] + 1) & ~1;
  int incl = pd;
#pragma unroll
  for (int o = 1; o < 64; o <<= 1) {
    int u = __shfl_up(incl, o, 64);
    if (l >= o) incl += u;
  }
  int base = 0;
  if (l == 63) base = atomicAdd(alloc, incl);
  base = __shfl(base, 63, 64);
  if (n < NN) { int p = base + incl - pd; row_ptr[n] = p; cursor[n] = p; }
}

// Counting scatter by dst (4 edges/thread) + c_raw accumulation.
__global__ void k_scatter(const int4* __restrict__ src4, const int4* __restrict__ dst4,
                          const int* __restrict__ deg_in, int* __restrict__ cursor,
                          int* __restrict__ slots, float* __restrict__ c_raw) {
  int i = blockIdx.x * blockDim.x + threadIdx.x;
  if (i < NE / 4) {
    int4 s = src4[i], d = dst4[i];
    int p0 = atomicAdd(&cursor[d.x], 1);
    int p1 = atomicAdd(&cursor[d.y], 1);
    int p2 = atomicAdd(&cursor[d.z], 1);
    int p3 = atomicAdd(&cursor[d.w], 1);
    slots[p0] = s.x; slots[p1] = s.y; slots[p2] = s.z; slots[p3] = s.w;
    atomicAdd(&c_raw[s.x], rsqrtf((float)max(deg_in[d.x], 1)));
    atomicAdd(&c_raw[s.y], rsqrtf((float)max(deg_in[d.y], 1)));
    atomicAdd(&c_raw[s.z], rsqrtf((float)max(deg_in[d.z], 1)));
    atomicAdd(&c_raw[s.w], rsqrtf((float)max(deg_in[d.w], 1)));
  }
}

// One wave per 4-node tile, static assignment, 2-deep ping-pong prefetch.
__global__ __launch_bounds__(256, 6)
void k_gather(const float* __restrict__ z,
              const int* __restrict__ deg_in, const int* __restrict__ deg_out,
              const float* __restrict__ c_raw,
              const int* __restrict__ row_ptr, const int* __restrict__ slots,
              const float* __restrict__ b1,
              const float* __restrict__ W2, const float* __restrict__ b2,
              const float* __restrict__ Wr, const float* __restrict__ br,
              int* __restrict__ ticket,
              float* __restrict__ svec, float* __restrict__ out) {
  __shared__ float red[96];
  __shared__ float sg[96], hg[96];
  __shared__ int lastflag;
  const int tid = threadIdx.x, l = tid & 63;
  const int ll = l & 31, half = l >> 5;
  if (tid < 96) red[tid] = 0.f;
  __syncthreads();

  float bb0 = b1[ll], bb1 = b1[ll + 32], bb2 = b1[ll + 64];
  float as0 = 0.f, as1 = 0.f, as2 = 0.f;

  const int NTILES = NN / 4;
  const int nworkers = gridDim.x * 4;
  for (int tile = blockIdx.x * 4 + (tid >> 6); tile < NTILES; tile += nworkers) {
    int n0 = tile * 4;

    int mrp = 0, mdi = 0, mdg = 0; float mcr = 0.f;
    if (l < 4)       mrp = row_ptr[n0 + l];
    else if (l < 8)  mdi = deg_in[n0 + (l - 4)];
    else if (l < 12) mdg = deg_out[n0 + (l - 8)];
    else if (l < 16) mcr = c_raw[n0 + (l - 12)];
    int rp0 = __shfl(mrp, 0, 64), rp1 = __shfl(mrp, 1, 64),
        rp2 = __shfl(mrp, 2, 64), rp3 = __shfl(mrp, 3, 64);
    int di0 = __shfl(mdi, 4, 64), di1 = __shfl(mdi, 5, 64),
        di2 = __shfl(mdi, 6, 64), di3 = __shfl(mdi, 7, 64);
    int bk0 = slots[rp0 + l], bk1 = slots[rp1 + l],
        bk2 = slots[rp2 + l], bk3 = slots[rp3 + l];

    float v00 = 0.f, v01 = 0.f, v02 = 0.f;
    float v10 = 0.f, v11 = 0.f, v12 = 0.f;
    float v20 = 0.f, v21 = 0.f, v22 = 0.f;
    float v30 = 0.f, v31 = 0.f, v32 = 0.f;

    auto fetchR = [&](int t, float* X) {
      int idx = t + half;
      int s0, s1, s2, s3;
      if (t < 64) {                               // wave-uniform branch
        s0 = __shfl(bk0, idx, 64); s1 = __shfl(bk1, idx, 64);
        s2 = __shfl(bk2, idx, 64); s3 = __shfl(bk3, idx, 64);
      } else {                                    // rare deg>64 fallback
        s0 = slots[min(rp0 + idx, SLOTS_CAP - 1)];
        s1 = slots[min(rp1 + idx, SLOTS_CAP - 1)];
        s2 = slots[min(rp2 + idx, SLOTS_CAP - 1)];
        s3 = slots[min(rp3 + idx, SLOTS_CAP - 1)];
      }
      s0 = (idx < di0) ? s0 : ZROW;
      s1 = (idx < di1) ? s1 : ZROW;
      s2 = (idx < di2) ? s2 : ZROW;
      s3 = (idx < di3) ? s3 : ZROW;
      const float* r0 = z + (size_t)s0 * 96 + ll;
      const float* r1 = z + (size_t)s1 * 96 + ll;
      const float* r2 = z + (size_t)s2 * 96 + ll;
      const float* r3 = z + (size_t)s3 * 96 + ll;
      X[0] = r0[0]; X[1]  = r0[32]; X[2]  = r0[64];
      X[3] = r1[0]; X[4]  = r1[32]; X[5]  = r1[64];
      X[6] = r2[0]; X[7]  = r2[32]; X[8]  = r2[64];
      X[9] = r3[0]; X[10] = r3[32]; X[11] = r3[64];
    };
    auto accR = [&](const float* X) {
      v00 += X[0]; v01 += X[1];  v02 += X[2];
      v10 += X[3]; v11 += X[4];  v12 += X[5];
      v20 += X[6]; v21 += X[7];  v22 += X[8];
      v30 += X[9]; v31 += X[10]; v32 += X[11];
    };

    int maxdi = max(max(di0, di1), max(di2, di3));
    float A[12], B[12];
    if (maxdi > 0) fetchR(0, A);
#pragma unroll 1
    for (int t = 0; t < maxdi; t += 4) {
      if (t + 2 < maxdi) fetchR(t + 2, B);
      accR(A);
      if (t + 4 < maxdi) fetchR(t + 4, A);
      if (t + 2 < maxdi) accR(B);
    }

    // fold halves (A holds even-edge partials, B odd-edge partials)
    v00 += __shfl_xor(v00, 32, 64); v01 += __shfl_xor(v01, 32, 64); v02 += __shfl_xor(v02, 32, 64);
    v10 += __shfl_xor(v10, 32, 64); v11 += __shfl_xor(v11, 32, 64); v12 += __shfl_xor(v12, 32, 64);
    v20 += __shfl_xor(v20, 32, 64); v21 += __shfl_xor(v21, 32, 64); v22 += __shfl_xor(v22, 32, 64);
    v30 += __shfl_xor(v30, 32, 64); v31 += __shfl_xor(v31, 32, 64); v32 += __shfl_xor(v32, 32, 64);

    int dg0 = __shfl(mdg, 8, 64),  dg1 = __shfl(mdg, 9, 64),
        dg2 = __shfl(mdg, 10, 64), dg3 = __shfl(mdg, 11, 64);
    float cr0 = __shfl(mcr, 12, 64), cr1 = __shfl(mcr, 13, 64),
          cr2 = __shfl(mcr, 14, 64), cr3 = __shfl(mcr, 15, 64);

    float ni, cw;
    ni = rsqrtf((float)max(di0, 1)); cw = rsqrtf((float)max(dg0, 1)) * cr0;
    as0 = fmaf(cw, fmaxf(fmaf(ni, v00, bb0), 0.f), as0);
    as1 = fmaf(cw, fmaxf(fmaf(ni, v01, bb1), 0.f), as1);
    as2 = fmaf(cw, fmaxf(fmaf(ni, v02, bb2), 0.f), as2);
    ni = rsqrtf((float)max(di1, 1)); cw = rsqrtf((float)max(dg1, 1)) * cr1;
    as0 = fmaf(cw, fmaxf(fmaf(ni, v10, bb0), 0.f), as0);
    as1 = fmaf(cw, fmaxf(fmaf(ni, v11, bb1), 0.f), as1);
    as2 = fmaf(cw, fmaxf(fmaf(ni, v12, bb2), 0.f), as2);
    ni = rsqrtf((float)max(di2, 1)); cw = rsqrtf((float)max(dg2, 1)) * cr2;
    as0 = fmaf(cw, fmaxf(fmaf(ni, v20, bb0), 0.f), as0);
    as1 = fmaf(cw, fmaxf(fmaf(ni, v21, bb1), 0.f), as1);
    as2 = fmaf(cw, fmaxf(fmaf(ni, v22, bb2), 0.f), as2);
    ni = rsqrtf((float)max(di3, 1)); cw = rsqrtf((float)max(dg3, 1)) * cr3;
    as0 = fmaf(cw, fmaxf(fmaf(ni, v30, bb0), 0.f), as0);
    as1 = fmaf(cw, fmaxf(fmaf(ni, v31, bb1), 0.f), as1);
    as2 = fmaf(cw, fmaxf(fmaf(ni, v32, bb2), 0.f), as2);
  }

  if (half == 0) {
    atomicAdd(&red[ll], as0);
    atomicAdd(&red[ll + 32], as1);
    atomicAdd(&red[ll + 64], as2);
  }
  __syncthreads();
  if (tid < 96) atomicAdd(&svec[tid], red[tid]);
  __threadfence();
  __syncthreads();
  if (tid == 0) {
    int tk = atomicAdd(ticket, 1);
    lastflag = (tk == (int)gridDim.x - 1);
  }
  __syncthreads();
  if (lastflag) {
    if (tid < 96) sg[tid] = atomicAdd(&svec[tid], 0.0f);
    __syncthreads();
    if (tid < 96) {
      float acc = b2[tid];
      const float invN = 1.0f / (float)NN;
      for (int k = 0; k < 96; ++k)
        acc = fmaf(sg[k] * invN, W2[k * 96 + tid], acc);
      hg[tid] = acc;
    }
    __syncthreads();
    if (tid < 8) {
      float acc = br[tid];
      for (int k = 0; k < 96; ++k)
        acc = fmaf(hg[k], Wr[tid * 96 + k], acc);
      out[tid] = acc;
    }
  }
}

extern "C" void kernel_launch(void* const* d_in, const int* in_sizes, int n_in,
                              void* d_out, int out_size, void* d_ws, size_t ws_size,
                              hipStream_t stream) {
  const float* feats = (const float*)d_in[0];
  const int*   src   = (const int*)d_in[1];
  const int*   dst   = (const int*)d_in[2];
  const float* W1    = (const float*)d_in[3];
  const float* b1    = (const float*)d_in[4];
  const float* W2    = (const float*)d_in[5];
  const float* b2    = (const float*)d_in[6];
  const float* Wr    = (const float*)d_in[7];
  const float* br    = (const float*)d_in[8];
  float* out = (float*)d_out;

  int*   wsi = (int*)d_ws;
  float* wsf = (float*)d_ws;
  int*   deg_out = wsi + OFF_DEG_OUT;
  int*   deg_in  = wsi + OFF_DEG_IN;
  float* c_raw   = wsf + OFF_CRAW;
  float* svec    = wsf + OFF_SVEC;
  int*   ticket  = wsi + OFF_TICKET;
  int*   alloc   = wsi + OFF_ALLOC;
  int*   row_ptr = wsi + OFF_ROW_PTR;
  int*   cursor  = wsi + OFF_CURSOR;
  int*   slots   = wsi + OFF_SLOTS;
  float* z       = wsf + OFF_Z;

  hipMemsetAsync(d_ws, 0, ZERO_DW * 4, stream);

  k_deg<<<(NE / 4 + 255) / 256, 256, 0, stream>>>((const int4*)src, (const int4*)dst,
                                                  deg_out, deg_in);
  k_gemm<<<1024, 256, 0, stream>>>(feats, deg_out, W1, z);
  k_alloc<<<(NN + 255) / 256, 256, 0, stream>>>(deg_in, alloc, row_ptr, cursor, z);
  k_scatter<<<(NE / 4 + 255) / 256, 256, 0, stream>>>((const int4*)src, (const int4*)dst,
                                                      deg_in, cursor, slots, c_raw);
  k_gather<<<2048, 256, 0, stream>>>(z, deg_in, deg_out, c_raw, row_ptr, slots,
                                     b1, W2, b2, Wr, br, ticket, svec, out);
}